// Round 6
// baseline (142.043 us; speedup 1.0000x reference)
//
#include <hip/hip_runtime.h>
#include <math.h>

// PointLaplacianLoss — grid-pruned exact KNN, round 6.
//
// Round-5 lesson: runtime-shaped run loop (r%Wd, r/Wd with runtime Wd) costs
// ~40 VALU ops/iter (gfx950 has no integer div) and blocks unrolling, adding
// ~20 us to phase1. Fix: wave-uniform reach via __any(q2>4.8) ballot, then a
// compile-time-specialized fully-unrolled scan (scan_neigh<1> = 9 runs,
// scan_neigh<2> = 25 runs). Everything else as round 5.
// The ~40 us fillBufferAligned per iter is the harness d_ws poison: fixed tax.

constexpr int NPTS  = 8192;
constexpr int NB    = 2;
constexpr int KNN   = 10;
constexpr int QPB   = 64;
constexpr int WPB   = 8;
constexpr int BLOCK = QPB * WPB;        // 512
constexpr int MASK13 = 0xFFFFE000;

constexpr int   G    = 32;
constexpr int   NC   = G * G * G;
constexpr float BMIN = -5.5f;
constexpr float BW   = 11.0f;
constexpr float H    = BW / G;          // 0.34375
constexpr float INVH = (float)G / BW;

// ---------------- selection helpers ----------------
__device__ __forceinline__ void ins1(int l[KNN], int x) {
#pragma unroll
    for (int k = KNN - 1; k > 0; --k) l[k] = min(l[k], max(l[k - 1], x));
    l[0] = min(l[0], x);
}
__device__ __forceinline__ void ins2(int l[KNN], int a, int b) {
    const int b0 = min(a, b), b1 = max(a, b);
#pragma unroll
    for (int k = KNN - 1; k >= 2; --k)
        l[k] = min(l[k], min(max(l[k - 1], b0), max(l[k - 2], b1)));
    l[1] = min(l[1], min(max(l[0], b0), b1));
    l[0] = min(l[0], b0);
}
// Pair (a,b)=(p[2i],p[2i+1]) from a SORTED source: merged rank >= 2i.
template<int S>
__device__ __forceinline__ void ins2s(int l[KNN], int a, int b) {
    const int b0 = min(a, b), b1 = max(a, b);
#pragma unroll
    for (int k = KNN - 1; k >= S + 2; --k)
        l[k] = min(l[k], min(max(l[k - 1], b0), max(l[k - 2], b1)));
    l[S + 1] = min(l[S + 1], min(max(l[S], b0), b1));
    l[S] = min(l[S], b0);
}
__device__ __forceinline__ void merge_sorted(int l[KNN], const int p[KNN]) {
    ins2s<0>(l, p[0], p[1]);
    ins2s<2>(l, p[2], p[3]);
    ins2s<4>(l, p[4], p[5]);
    ins2s<6>(l, p[6], p[7]);
    ins2s<8>(l, p[8], p[9]);
}

// ---------------- build kernels ----------------
__global__ void pack_bin(const float* __restrict__ p1, float4* __restrict__ w,
                         int* __restrict__ hist, int* __restrict__ cellof) {
    const int i = blockIdx.x * blockDim.x + threadIdx.x;
    if (i >= NB * NPTS) return;
    const float x = p1[3 * i], y = p1[3 * i + 1], z = p1[3 * i + 2];
    w[i] = make_float4(x, y, z, fmaf(x, x, fmaf(y, y, z * z)));
    const int cx = min(max((int)floorf((x - BMIN) * INVH), 0), G - 1);
    const int cy = min(max((int)floorf((y - BMIN) * INVH), 0), G - 1);
    const int cz = min(max((int)floorf((z - BMIN) * INVH), 0), G - 1);
    const int c = (cz << 10) | (cy << 5) | cx;
    cellof[i] = c;
    atomicAdd(&hist[(i >> 13) * NC + c], 1);
}

__global__ __launch_bounds__(1024)
void scan_cells(const int* __restrict__ hist, int* __restrict__ starts,
                float* __restrict__ out, int* __restrict__ nfail) {
    __shared__ int wsum[16];
    const int b = blockIdx.x, t = threadIdx.x;
    if (b == 0 && t == 0) { out[0] = 0.0f; nfail[0] = 0; }
    const int* hb = hist + b * NC;
    int* sb = starts + b * (NC + 1);
    const int c0 = t * 32;
    int loc[32]; int sum = 0;
#pragma unroll
    for (int j = 0; j < 32; ++j) { loc[j] = hb[c0 + j]; sum += loc[j]; }
    const int lane = t & 63, wv = t >> 6;
    int incl = sum;
#pragma unroll
    for (int off = 1; off < 64; off <<= 1) {
        const int v = __shfl_up(incl, off);
        if (lane >= off) incl += v;
    }
    if (lane == 63) wsum[wv] = incl;
    __syncthreads();
    if (t < 16) {
        const int v = wsum[t];
        int iv = v;
#pragma unroll
        for (int off = 1; off < 16; off <<= 1) {
            const int u = __shfl_up(iv, off);
            if (t >= off) iv += u;
        }
        wsum[t] = iv - v;
    }
    __syncthreads();
    int run = wsum[wv] + incl - sum;
#pragma unroll
    for (int j = 0; j < 32; ++j) { sb[c0 + j] = run; run += loc[j]; }
    if (t == 1023) sb[NC] = run;
}

__global__ void scatter_all(const int* __restrict__ cellof,
                            const int* __restrict__ starts,
                            int* __restrict__ hist,
                            const float4* __restrict__ w,
                            const float* __restrict__ p2,
                            float4* __restrict__ wsorted,
                            float4* __restrict__ p2s) {
    const int i = blockIdx.x * blockDim.x + threadIdx.x;
    if (i >= NB * NPTS) return;
    const int b = i >> 13;
    const int c = cellof[i];
    const int old = atomicSub(&hist[b * NC + c], 1);
    const int pos = b * NPTS + starts[b * (NC + 1) + c] + old - 1;
    wsorted[pos] = w[i];
    p2s[pos] = make_float4(p2[3 * i], p2[3 * i + 1], p2[3 * i + 2], 0.0f);
}

// ---------------- phase 1: compile-time-specialized neighborhood scan -------
template<int S>
__device__ __forceinline__ void scan_neigh(const float4* __restrict__ W,
                                           const int* __restrict__ st,
                                           int cx, int cy, int cz,
                                           float m2x, float m2y, float m2z,
                                           float q2, int qpos, int wv,
                                           int l[KNN])
{
    const int IMAX = 0x7FFFFFFF;
    constexpr int Wd = 2 * S + 1;
#pragma unroll
    for (int r = 0; r < Wd * Wd; ++r) {
        const int dy = r % Wd - S, dz = r / Wd - S;   // compile-time constants
        const int ay = cy + dy, az = cz + dz;
        int j0 = 0, j1 = 0;
        if ((unsigned)ay < G && (unsigned)az < G) {
            const int cbase = (az << 10) | (ay << 5);
            j0 = st[cbase + max(cx - S, 0)];
            j1 = st[cbase + min(cx + S, G - 1) + 1];
        }
        for (int j = j0 + wv; j < j1; j += WPB) {
            const float4 c4 = W[j];
            const float d2 = fmaf(m2x, c4.x,
                             fmaf(m2y, c4.y,
                             fmaf(m2z, c4.z, c4.w + q2)));
            int key = (__float_as_int(d2) & MASK13) | j;
            key = (j == qpos) ? IMAX : key;
            ins1(l, key);
        }
    }
}

__global__ __launch_bounds__(BLOCK)
void phase1(const float4* __restrict__ wsorted, const float4* __restrict__ p2s,
            const int* __restrict__ starts, float* __restrict__ out,
            int* __restrict__ nfail, int* __restrict__ worklist)
{
    __shared__ int mv[WPB * KNN * QPB];      // 20 KB

    const int batch = blockIdx.x >> 7;
    const int lane  = threadIdx.x & 63;
    const int wv    = __builtin_amdgcn_readfirstlane(threadIdx.x >> 6);
    const int qpos  = ((blockIdx.x & 127) << 6) + lane;

    const float4* W  = wsorted + batch * NPTS;
    const float4* P2 = p2s + batch * NPTS;
    const int*    st = starts + batch * (NC + 1);

    const float4 qp = W[qpos];
    const int cx = min(max((int)floorf((qp.x - BMIN) * INVH), 0), G - 1);
    const int cy = min(max((int)floorf((qp.y - BMIN) * INVH), 0), G - 1);
    const int cz = min(max((int)floorf((qp.z - BMIN) * INVH), 0), G - 1);
    const float lox = BMIN + cx * H, loy = BMIN + cy * H, loz = BMIN + cz * H;
    const float df = fminf(fminf(fminf(qp.x - lox, lox + H - qp.x),
                                 fminf(qp.y - loy, loy + H - qp.y)),
                           fminf(qp.z - loz, loz + H - qp.z));
    const float m2x = -2.0f * qp.x, m2y = -2.0f * qp.y, m2z = -2.0f * qp.z;
    const float q2 = qp.w;
    const int IMAX = 0x7FFFFFFF;

    // wave-uniform reach: all 8 wave-slices of a block see the same 64
    // queries -> identical ballot -> coverage check below is consistent.
    const bool sparse = __any(q2 > 4.8f);
    const int s = sparse ? 2 : 1;

    int l[KNN];
#pragma unroll
    for (int k = 0; k < KNN; ++k) l[k] = IMAX;

    if (sparse)
        scan_neigh<2>(W, st, cx, cy, cz, m2x, m2y, m2z, q2, qpos, wv, l);
    else
        scan_neigh<1>(W, st, cx, cy, cz, m2x, m2y, m2z, q2, qpos, wv, l);

#pragma unroll
    for (int k = 0; k < KNN; ++k) mv[(wv * KNN + k) * QPB + lane] = l[k];
    __syncthreads();

    if (threadIdx.x < QPB) {
        int M[KNN];
#pragma unroll
        for (int k = 0; k < KNN; ++k) M[k] = IMAX;
#pragma unroll
        for (int e = 0; e < WPB; ++e) {
            int p[KNN];
#pragma unroll
            for (int k = 0; k < KNN; ++k) p[k] = mv[(e * KNN + k) * QPB + lane];
            merge_sorted(M, p);
        }

        const float tau = __int_as_float(M[KNN - 1] & MASK13);
        const float R = (float)s * H + df;            // guaranteed coverage
        const bool covered = (tau <= R * R * 0.996f); // truncation margin
        float v = 0.0f;
        if (covered) {
            float s1x = 0, s1y = 0, s1z = 0, s2x = 0, s2y = 0, s2z = 0;
#pragma unroll
            for (int k = 0; k < KNN; ++k) {
                const int j = M[k] & (NPTS - 1);
                const float4 c4 = W[j];
                const float4 n2 = P2[j];
                s1x += c4.x; s1y += c4.y; s1z += c4.z;
                s2x += n2.x; s2y += n2.y; s2z += n2.z;
            }
            const float4 p2v = P2[qpos];
            const float dx = (s1x * 0.1f - qp.x) - (s2x * 0.1f - p2v.x);
            const float dy2 = (s1y * 0.1f - qp.y) - (s2y * 0.1f - p2v.y);
            const float dz2 = (s1z * 0.1f - qp.z) - (s2z * 0.1f - p2v.z);
            v = fabsf(dx) + fabsf(dy2) + fabsf(dz2);
        } else {
            const int wi = atomicAdd(nfail, 1);
            worklist[wi] = (batch << 16) | qpos;
        }
#pragma unroll
        for (int off = 32; off >= 1; off >>= 1) v += __shfl_down(v, off);
        if (threadIdx.x == 0)
            atomicAdd(out, v * (1.0f / (float)(NB * NPTS * 3)));
    }
}

// ---------------- phase 2: wave-per-query exact brute force ----------------
constexpr int P2BLK = 256;     // 4 waves/block
constexpr int P2GRID = 512;    // 2048 waves

__global__ __launch_bounds__(P2BLK)
void phase2(const float4* __restrict__ wsorted, const float4* __restrict__ p2s,
            const int* __restrict__ nfail, const int* __restrict__ worklist,
            float* __restrict__ out)
{
    const int lane = threadIdx.x & 63;
    const int wv   = threadIdx.x >> 6;
    const int wid  = blockIdx.x * (P2BLK / 64) + wv;
    const int NW   = P2GRID * (P2BLK / 64);
    const int nf   = *nfail;
    const int IMAX = 0x7FFFFFFF;
    float acc = 0.0f;

    for (int i = wid; i < nf; i += NW) {
        const int e = worklist[i];
        const int batch = e >> 16, qpos = e & 0xFFFF;
        const float4* W  = wsorted + batch * NPTS;
        const float4* P2 = p2s + batch * NPTS;
        const float4 qp = W[qpos];
        const float m2x = -2.0f * qp.x, m2y = -2.0f * qp.y, m2z = -2.0f * qp.z;
        const float q2 = qp.w;

        int l[KNN];
#pragma unroll
        for (int k = 0; k < KNN; ++k) l[k] = IMAX;

#pragma unroll 2
        for (int it = 0; it < NPTS / 128; ++it) {
            const int ja = it * 128 + lane, jb = ja + 64;
            const float4 ca = W[ja];
            const float4 cb = W[jb];
            const float da = fmaf(m2x, ca.x, fmaf(m2y, ca.y, fmaf(m2z, ca.z, ca.w + q2)));
            const float db = fmaf(m2x, cb.x, fmaf(m2y, cb.y, fmaf(m2z, cb.z, cb.w + q2)));
            int ka = (__float_as_int(da) & MASK13) | ja;
            int kb = (__float_as_int(db) & MASK13) | jb;
            ka = (ja == qpos) ? IMAX : ka;
            kb = (jb == qpos) ? IMAX : kb;
            ins2(l, ka, kb);
        }
        for (int off = 1; off < 64; off <<= 1) {
            int p[KNN];
#pragma unroll
            for (int k = 0; k < KNN; ++k) p[k] = __shfl_xor(l[k], off);
            merge_sorted(l, p);
        }
        float s1x = 0, s1y = 0, s1z = 0, s2x = 0, s2y = 0, s2z = 0;
#pragma unroll
        for (int k = 0; k < KNN; ++k) {
            const int j = l[k] & (NPTS - 1);
            const float4 c4 = W[j];
            const float4 n2 = P2[j];
            s1x += c4.x; s1y += c4.y; s1z += c4.z;
            s2x += n2.x; s2y += n2.y; s2z += n2.z;
        }
        const float4 p2v = P2[qpos];
        const float dx = (s1x * 0.1f - qp.x) - (s2x * 0.1f - p2v.x);
        const float dy = (s1y * 0.1f - qp.y) - (s2y * 0.1f - p2v.y);
        const float dz = (s1z * 0.1f - qp.z) - (s2z * 0.1f - p2v.z);
        if (lane == 0) acc += fabsf(dx) + fabsf(dy) + fabsf(dz);
    }

    if (lane == 0 && acc != 0.0f)
        atomicAdd(out, acc * (1.0f / (float)(NB * NPTS * 3)));
}

// ---------------- round-2 fallback (O(N^2), verified) ----------------
constexpr int CHUNK = NPTS / WPB;

__global__ void prep_pack(const float* __restrict__ p, float4* __restrict__ w) {
    const int i = blockIdx.x * blockDim.x + threadIdx.x;
    if (i < NB * NPTS) {
        const float x = p[3 * i], y = p[3 * i + 1], z = p[3 * i + 2];
        w[i] = make_float4(x, y, z, fmaf(x, x, fmaf(y, y, z * z)));
    }
}

__global__ __launch_bounds__(BLOCK, 2)
void knn_lap(const float4* __restrict__ w1, const float* __restrict__ p2,
             float* __restrict__ out)
{
    __shared__ int mv[WPB * KNN * QPB];
    const int batch = blockIdx.x >> 7;
    const int qbase = (blockIdx.x & 127) << 6;
    const int lane  = threadIdx.x & 63;
    const int wv    = __builtin_amdgcn_readfirstlane(threadIdx.x >> 6);
    const int query = qbase + lane;
    const float4* Wb = w1 + batch * NPTS;
    const float4 qp = Wb[query];
    const float m2x = -2.0f * qp.x, m2y = -2.0f * qp.y, m2z = -2.0f * qp.z;
    const float q2 = qp.w;
    const int IMAX = 0x7FFFFFFF;
    int l[KNN];
#pragma unroll
    for (int k = 0; k < KNN; ++k) l[k] = IMAX;
    const int c0 = wv * CHUNK;
    const float4* cand = Wb + c0;
#pragma unroll 4
    for (int i = 0; i < CHUNK; i += 2) {
        const float4 ca = cand[i];
        const float4 cb = cand[i + 1];
        const int ja = c0 + i, jb = ja + 1;
        const float da = fmaf(m2x, ca.x, fmaf(m2y, ca.y, fmaf(m2z, ca.z, ca.w + q2)));
        const float db = fmaf(m2x, cb.x, fmaf(m2y, cb.y, fmaf(m2z, cb.z, cb.w + q2)));
        int ka = (__float_as_int(da) & MASK13) | ja;
        int kb = (__float_as_int(db) & MASK13) | jb;
        ka = (ja == query) ? IMAX : ka;
        kb = (jb == query) ? IMAX : kb;
        ins2(l, ka, kb);
    }
#pragma unroll
    for (int k = 0; k < KNN; ++k) mv[(wv * KNN + k) * QPB + lane] = l[k];
    __syncthreads();
    if (threadIdx.x < QPB) {
        int m[KNN];
#pragma unroll
        for (int k = 0; k < KNN; ++k) m[k] = IMAX;
#pragma unroll
        for (int e = 0; e < WPB; ++e) {
            int p[KNN];
#pragma unroll
            for (int k = 0; k < KNN; ++k) p[k] = mv[(e * KNN + k) * QPB + lane];
            merge_sorted(m, p);
        }
        const float* P2b = p2 + (size_t)batch * NPTS * 3;
        float s1x = 0, s1y = 0, s1z = 0, s2x = 0, s2y = 0, s2z = 0;
#pragma unroll
        for (int k = 0; k < KNN; ++k) {
            const int j = m[k] & (NPTS - 1);
            const float4 c = Wb[j];
            s1x += c.x; s1y += c.y; s1z += c.z;
            s2x += P2b[3 * j + 0]; s2y += P2b[3 * j + 1]; s2z += P2b[3 * j + 2];
        }
        const int q = qbase + threadIdx.x;
        const float p2x = P2b[3 * q + 0], p2y = P2b[3 * q + 1], p2z = P2b[3 * q + 2];
        const float dx = (s1x * 0.1f - qp.x) - (s2x * 0.1f - p2x);
        const float dy = (s1y * 0.1f - qp.y) - (s2y * 0.1f - p2y);
        const float dz = (s1z * 0.1f - qp.z) - (s2z * 0.1f - p2z);
        float v = fabsf(dx) + fabsf(dy) + fabsf(dz);
#pragma unroll
        for (int off = 32; off >= 1; off >>= 1) v += __shfl_down(v, off);
        if (threadIdx.x == 0)
            atomicAdd(out, v * (1.0f / (float)(NB * NPTS * 3)));
    }
}

// ---------------- launcher ----------------
extern "C" void kernel_launch(void* const* d_in, const int* in_sizes, int n_in,
                              void* d_out, int out_size, void* d_ws, size_t ws_size,
                              hipStream_t stream) {
    const float* p1 = (const float*)d_in[0];
    const float* p2 = (const float*)d_in[1];
    float* out = (float*)d_out;

    size_t off = 0;
    float4* w       = (float4*)d_ws;               off += (size_t)NB * NPTS * 16;
    int*    hist    = (int*)((char*)d_ws + off);   off += (size_t)NB * NC * 4;
    int*    starts  = (int*)((char*)d_ws + off);   off += (size_t)NB * (NC + 1) * 4 + 8;
    int*    cellof  = (int*)((char*)d_ws + off);   off += (size_t)NB * NPTS * 4;
    float4* wsorted = (float4*)((char*)d_ws + off); off += (size_t)NB * NPTS * 16;
    float4* p2s     = (float4*)((char*)d_ws + off); off += (size_t)NB * NPTS * 16;
    int*    nfail   = (int*)((char*)d_ws + off);   off += 16;
    int*    worklist= (int*)((char*)d_ws + off);   off += (size_t)NB * NPTS * 4;

    if (ws_size < off) {  // fallback: round-2 brute force
        hipMemsetAsync(out, 0, sizeof(float), stream);
        prep_pack<<<(NB * NPTS + 255) / 256, 256, 0, stream>>>(p1, w);
        knn_lap<<<NB * (NPTS / QPB), BLOCK, 0, stream>>>(w, p2, out);
        return;
    }

    hipMemsetAsync(hist, 0, (size_t)NB * NC * 4, stream);
    pack_bin<<<(NB * NPTS + 255) / 256, 256, 0, stream>>>(p1, w, hist, cellof);
    scan_cells<<<NB, 1024, 0, stream>>>(hist, starts, out, nfail);
    scatter_all<<<(NB * NPTS + 255) / 256, 256, 0, stream>>>(cellof, starts, hist,
                                                             w, p2, wsorted, p2s);
    phase1<<<NB * (NPTS / QPB), BLOCK, 0, stream>>>(wsorted, p2s, starts, out,
                                                    nfail, worklist);
    phase2<<<P2GRID, P2BLK, 0, stream>>>(wsorted, p2s, nfail, worklist, out);
}

// Round 7
// 121.948 us; speedup vs baseline: 1.1648x; 1.1648x over previous
//
#include <hip/hip_runtime.h>
#include <math.h>

// PointLaplacianLoss — grid-pruned exact KNN, round 7.
//
// Round-6 lesson: wave-uniform 5^3 promotion made mixed waves near the shell
// boundary scan ~600 dense candidates (53 us, VALUBusy 20%). Revert to
// per-lane adaptive reach (round-5 semantics, exec-masked), but div-free:
// dy,dz via magic-mul r/3=(r*86)>>8, r/5=(r*52429)>>18 + cndmask select.
// All-dense waves exit the r-loop after 9 iters (__any ballot). The j-loop
// prefetches the next candidate before inserting the current one to overlap
// the ~200-cyc L2 latency (phase1 runs at 2 waves/SIMD — TLP can't hide it).

constexpr int NPTS  = 8192;
constexpr int NB    = 2;
constexpr int KNN   = 10;
constexpr int QPB   = 64;
constexpr int WPB   = 8;
constexpr int BLOCK = QPB * WPB;        // 512
constexpr int MASK13 = 0xFFFFE000;

constexpr int   G    = 32;
constexpr int   NC   = G * G * G;
constexpr float BMIN = -5.5f;
constexpr float BW   = 11.0f;
constexpr float H    = BW / G;          // 0.34375
constexpr float INVH = (float)G / BW;

// ---------------- selection helpers ----------------
__device__ __forceinline__ void ins1(int l[KNN], int x) {
#pragma unroll
    for (int k = KNN - 1; k > 0; --k) l[k] = min(l[k], max(l[k - 1], x));
    l[0] = min(l[0], x);
}
__device__ __forceinline__ void ins2(int l[KNN], int a, int b) {
    const int b0 = min(a, b), b1 = max(a, b);
#pragma unroll
    for (int k = KNN - 1; k >= 2; --k)
        l[k] = min(l[k], min(max(l[k - 1], b0), max(l[k - 2], b1)));
    l[1] = min(l[1], min(max(l[0], b0), b1));
    l[0] = min(l[0], b0);
}
// Pair (a,b)=(p[2i],p[2i+1]) from a SORTED source: merged rank >= 2i.
template<int S>
__device__ __forceinline__ void ins2s(int l[KNN], int a, int b) {
    const int b0 = min(a, b), b1 = max(a, b);
#pragma unroll
    for (int k = KNN - 1; k >= S + 2; --k)
        l[k] = min(l[k], min(max(l[k - 1], b0), max(l[k - 2], b1)));
    l[S + 1] = min(l[S + 1], min(max(l[S], b0), b1));
    l[S] = min(l[S], b0);
}
__device__ __forceinline__ void merge_sorted(int l[KNN], const int p[KNN]) {
    ins2s<0>(l, p[0], p[1]);
    ins2s<2>(l, p[2], p[3]);
    ins2s<4>(l, p[4], p[5]);
    ins2s<6>(l, p[6], p[7]);
    ins2s<8>(l, p[8], p[9]);
}

// ---------------- build kernels ----------------
__global__ void pack_bin(const float* __restrict__ p1, float4* __restrict__ w,
                         int* __restrict__ hist, int* __restrict__ cellof) {
    const int i = blockIdx.x * blockDim.x + threadIdx.x;
    if (i >= NB * NPTS) return;
    const float x = p1[3 * i], y = p1[3 * i + 1], z = p1[3 * i + 2];
    w[i] = make_float4(x, y, z, fmaf(x, x, fmaf(y, y, z * z)));
    const int cx = min(max((int)floorf((x - BMIN) * INVH), 0), G - 1);
    const int cy = min(max((int)floorf((y - BMIN) * INVH), 0), G - 1);
    const int cz = min(max((int)floorf((z - BMIN) * INVH), 0), G - 1);
    const int c = (cz << 10) | (cy << 5) | cx;
    cellof[i] = c;
    atomicAdd(&hist[(i >> 13) * NC + c], 1);
}

__global__ __launch_bounds__(1024)
void scan_cells(const int* __restrict__ hist, int* __restrict__ starts,
                float* __restrict__ out, int* __restrict__ nfail) {
    __shared__ int wsum[16];
    const int b = blockIdx.x, t = threadIdx.x;
    if (b == 0 && t == 0) { out[0] = 0.0f; nfail[0] = 0; }
    const int* hb = hist + b * NC;
    int* sb = starts + b * (NC + 1);
    const int c0 = t * 32;
    int loc[32]; int sum = 0;
#pragma unroll
    for (int j = 0; j < 32; ++j) { loc[j] = hb[c0 + j]; sum += loc[j]; }
    const int lane = t & 63, wv = t >> 6;
    int incl = sum;
#pragma unroll
    for (int off = 1; off < 64; off <<= 1) {
        const int v = __shfl_up(incl, off);
        if (lane >= off) incl += v;
    }
    if (lane == 63) wsum[wv] = incl;
    __syncthreads();
    if (t < 16) {
        const int v = wsum[t];
        int iv = v;
#pragma unroll
        for (int off = 1; off < 16; off <<= 1) {
            const int u = __shfl_up(iv, off);
            if (t >= off) iv += u;
        }
        wsum[t] = iv - v;
    }
    __syncthreads();
    int run = wsum[wv] + incl - sum;
#pragma unroll
    for (int j = 0; j < 32; ++j) { sb[c0 + j] = run; run += loc[j]; }
    if (t == 1023) sb[NC] = run;
}

__global__ void scatter_all(const int* __restrict__ cellof,
                            const int* __restrict__ starts,
                            int* __restrict__ hist,
                            const float4* __restrict__ w,
                            const float* __restrict__ p2,
                            float4* __restrict__ wsorted,
                            float4* __restrict__ p2s) {
    const int i = blockIdx.x * blockDim.x + threadIdx.x;
    if (i >= NB * NPTS) return;
    const int b = i >> 13;
    const int c = cellof[i];
    const int old = atomicSub(&hist[b * NC + c], 1);
    const int pos = b * NPTS + starts[b * (NC + 1) + c] + old - 1;
    wsorted[pos] = w[i];
    p2s[pos] = make_float4(p2[3 * i], p2[3 * i + 1], p2[3 * i + 2], 0.0f);
}

// ---------------- phase 1: per-lane adaptive 3^3 / 5^3 scan ----------------
__global__ __launch_bounds__(BLOCK)
void phase1(const float4* __restrict__ wsorted, const float4* __restrict__ p2s,
            const int* __restrict__ starts, float* __restrict__ out,
            int* __restrict__ nfail, int* __restrict__ worklist)
{
    __shared__ int mv[WPB * KNN * QPB];      // 20 KB

    const int batch = blockIdx.x >> 7;
    const int lane  = threadIdx.x & 63;
    const int wv    = __builtin_amdgcn_readfirstlane(threadIdx.x >> 6);
    const int qpos  = ((blockIdx.x & 127) << 6) + lane;

    const float4* W  = wsorted + batch * NPTS;
    const float4* P2 = p2s + batch * NPTS;
    const int*    st = starts + batch * (NC + 1);

    const float4 qp = W[qpos];
    const int cx = min(max((int)floorf((qp.x - BMIN) * INVH), 0), G - 1);
    const int cy = min(max((int)floorf((qp.y - BMIN) * INVH), 0), G - 1);
    const int cz = min(max((int)floorf((qp.z - BMIN) * INVH), 0), G - 1);
    const float lox = BMIN + cx * H, loy = BMIN + cy * H, loz = BMIN + cz * H;
    const float df = fminf(fminf(fminf(qp.x - lox, lox + H - qp.x),
                                 fminf(qp.y - loy, loy + H - qp.y)),
                           fminf(qp.z - loz, loz + H - qp.z));
    const float m2x = -2.0f * qp.x, m2y = -2.0f * qp.y, m2z = -2.0f * qp.z;
    const float q2 = qp.w;
    const int IMAX = 0x7FFFFFFF;

    // per-lane reach (exec-masked): only truly-sparse lanes pay 5^3, and
    // their far-out cells are nearly empty.
    const int s    = (q2 > 4.8f) ? 2 : 1;
    const int runs = (s == 1) ? 9 : 25;

    int l[KNN];
#pragma unroll
    for (int k = 0; k < KNN; ++k) l[k] = IMAX;

    for (int r = 0; r < 25; ++r) {
        if (!__any(r < runs)) break;            // all-dense wave: stop at 9
        if (r < runs) {
            // div-free run->(dy,dz): r/3=(r*86)>>8 (r<9), r/5=(r*52429)>>18 (r<25)
            int dz3 = (r * 86) >> 8;
            const int dy3 = r - 3 * dz3 - 1;  dz3 -= 1;
            int dz5 = (r * 52429) >> 18;
            const int dy5 = r - 5 * dz5 - 2;  dz5 -= 2;
            const int dy = (s == 1) ? dy3 : dy5;
            const int dz = (s == 1) ? dz3 : dz5;
            const int ay = cy + dy, az = cz + dz;
            int j0 = 0, j1 = 0;
            if ((unsigned)ay < G && (unsigned)az < G) {
                const int cbase = (az << 10) | (ay << 5);
                j0 = st[cbase + max(cx - s, 0)];
                j1 = st[cbase + min(cx + s, G - 1) + 1];
            }
            int j = j0 + wv;
            if (j < j1) {
                float4 c4 = W[j];                       // prime
                while (true) {
                    const int jn = j + WPB;
                    const bool more = jn < j1;
                    float4 nx;
                    if (more) nx = W[jn];               // prefetch next
                    const float d2 = fmaf(m2x, c4.x,
                                     fmaf(m2y, c4.y,
                                     fmaf(m2z, c4.z, c4.w + q2)));
                    int key = (__float_as_int(d2) & MASK13) | j;
                    key = (j == qpos) ? IMAX : key;
                    ins1(l, key);
                    if (!more) break;
                    c4 = nx; j = jn;
                }
            }
        }
    }

#pragma unroll
    for (int k = 0; k < KNN; ++k) mv[(wv * KNN + k) * QPB + lane] = l[k];
    __syncthreads();

    if (threadIdx.x < QPB) {
        int M[KNN];
#pragma unroll
        for (int k = 0; k < KNN; ++k) M[k] = IMAX;
#pragma unroll
        for (int e = 0; e < WPB; ++e) {
            int p[KNN];
#pragma unroll
            for (int k = 0; k < KNN; ++k) p[k] = mv[(e * KNN + k) * QPB + lane];
            merge_sorted(M, p);
        }

        const float tau = __int_as_float(M[KNN - 1] & MASK13);
        const float R = (float)s * H + df;            // per-lane guaranteed coverage
        const bool covered = (tau <= R * R * 0.996f); // truncation margin
        float v = 0.0f;
        if (covered) {
            float s1x = 0, s1y = 0, s1z = 0, s2x = 0, s2y = 0, s2z = 0;
#pragma unroll
            for (int k = 0; k < KNN; ++k) {
                const int j = M[k] & (NPTS - 1);
                const float4 c4 = W[j];
                const float4 n2 = P2[j];
                s1x += c4.x; s1y += c4.y; s1z += c4.z;
                s2x += n2.x; s2y += n2.y; s2z += n2.z;
            }
            const float4 p2v = P2[qpos];
            const float dx = (s1x * 0.1f - qp.x) - (s2x * 0.1f - p2v.x);
            const float dy2 = (s1y * 0.1f - qp.y) - (s2y * 0.1f - p2v.y);
            const float dz2 = (s1z * 0.1f - qp.z) - (s2z * 0.1f - p2v.z);
            v = fabsf(dx) + fabsf(dy2) + fabsf(dz2);
        } else {
            const int wi = atomicAdd(nfail, 1);
            worklist[wi] = (batch << 16) | qpos;
        }
#pragma unroll
        for (int off = 32; off >= 1; off >>= 1) v += __shfl_down(v, off);
        if (threadIdx.x == 0)
            atomicAdd(out, v * (1.0f / (float)(NB * NPTS * 3)));
    }
}

// ---------------- phase 2: wave-per-query exact brute force ----------------
constexpr int P2BLK = 256;     // 4 waves/block
constexpr int P2GRID = 512;    // 2048 waves

__global__ __launch_bounds__(P2BLK)
void phase2(const float4* __restrict__ wsorted, const float4* __restrict__ p2s,
            const int* __restrict__ nfail, const int* __restrict__ worklist,
            float* __restrict__ out)
{
    const int lane = threadIdx.x & 63;
    const int wv   = threadIdx.x >> 6;
    const int wid  = blockIdx.x * (P2BLK / 64) + wv;
    const int NW   = P2GRID * (P2BLK / 64);
    const int nf   = *nfail;
    const int IMAX = 0x7FFFFFFF;
    float acc = 0.0f;

    for (int i = wid; i < nf; i += NW) {
        const int e = worklist[i];
        const int batch = e >> 16, qpos = e & 0xFFFF;
        const float4* W  = wsorted + batch * NPTS;
        const float4* P2 = p2s + batch * NPTS;
        const float4 qp = W[qpos];
        const float m2x = -2.0f * qp.x, m2y = -2.0f * qp.y, m2z = -2.0f * qp.z;
        const float q2 = qp.w;

        int l[KNN];
#pragma unroll
        for (int k = 0; k < KNN; ++k) l[k] = IMAX;

#pragma unroll 2
        for (int it = 0; it < NPTS / 128; ++it) {
            const int ja = it * 128 + lane, jb = ja + 64;
            const float4 ca = W[ja];
            const float4 cb = W[jb];
            const float da = fmaf(m2x, ca.x, fmaf(m2y, ca.y, fmaf(m2z, ca.z, ca.w + q2)));
            const float db = fmaf(m2x, cb.x, fmaf(m2y, cb.y, fmaf(m2z, cb.z, cb.w + q2)));
            int ka = (__float_as_int(da) & MASK13) | ja;
            int kb = (__float_as_int(db) & MASK13) | jb;
            ka = (ja == qpos) ? IMAX : ka;
            kb = (jb == qpos) ? IMAX : kb;
            ins2(l, ka, kb);
        }
        for (int off = 1; off < 64; off <<= 1) {
            int p[KNN];
#pragma unroll
            for (int k = 0; k < KNN; ++k) p[k] = __shfl_xor(l[k], off);
            merge_sorted(l, p);
        }
        float s1x = 0, s1y = 0, s1z = 0, s2x = 0, s2y = 0, s2z = 0;
#pragma unroll
        for (int k = 0; k < KNN; ++k) {
            const int j = l[k] & (NPTS - 1);
            const float4 c4 = W[j];
            const float4 n2 = P2[j];
            s1x += c4.x; s1y += c4.y; s1z += c4.z;
            s2x += n2.x; s2y += n2.y; s2z += n2.z;
        }
        const float4 p2v = P2[qpos];
        const float dx = (s1x * 0.1f - qp.x) - (s2x * 0.1f - p2v.x);
        const float dy = (s1y * 0.1f - qp.y) - (s2y * 0.1f - p2v.y);
        const float dz = (s1z * 0.1f - qp.z) - (s2z * 0.1f - p2v.z);
        if (lane == 0) acc += fabsf(dx) + fabsf(dy) + fabsf(dz);
    }

    if (lane == 0 && acc != 0.0f)
        atomicAdd(out, acc * (1.0f / (float)(NB * NPTS * 3)));
}

// ---------------- round-2 fallback (O(N^2), verified) ----------------
constexpr int CHUNK = NPTS / WPB;

__global__ void prep_pack(const float* __restrict__ p, float4* __restrict__ w) {
    const int i = blockIdx.x * blockDim.x + threadIdx.x;
    if (i < NB * NPTS) {
        const float x = p[3 * i], y = p[3 * i + 1], z = p[3 * i + 2];
        w[i] = make_float4(x, y, z, fmaf(x, x, fmaf(y, y, z * z)));
    }
}

__global__ __launch_bounds__(BLOCK, 2)
void knn_lap(const float4* __restrict__ w1, const float* __restrict__ p2,
             float* __restrict__ out)
{
    __shared__ int mv[WPB * KNN * QPB];
    const int batch = blockIdx.x >> 7;
    const int qbase = (blockIdx.x & 127) << 6;
    const int lane  = threadIdx.x & 63;
    const int wv    = __builtin_amdgcn_readfirstlane(threadIdx.x >> 6);
    const int query = qbase + lane;
    const float4* Wb = w1 + batch * NPTS;
    const float4 qp = Wb[query];
    const float m2x = -2.0f * qp.x, m2y = -2.0f * qp.y, m2z = -2.0f * qp.z;
    const float q2 = qp.w;
    const int IMAX = 0x7FFFFFFF;
    int l[KNN];
#pragma unroll
    for (int k = 0; k < KNN; ++k) l[k] = IMAX;
    const int c0 = wv * CHUNK;
    const float4* cand = Wb + c0;
#pragma unroll 4
    for (int i = 0; i < CHUNK; i += 2) {
        const float4 ca = cand[i];
        const float4 cb = cand[i + 1];
        const int ja = c0 + i, jb = ja + 1;
        const float da = fmaf(m2x, ca.x, fmaf(m2y, ca.y, fmaf(m2z, ca.z, ca.w + q2)));
        const float db = fmaf(m2x, cb.x, fmaf(m2y, cb.y, fmaf(m2z, cb.z, cb.w + q2)));
        int ka = (__float_as_int(da) & MASK13) | ja;
        int kb = (__float_as_int(db) & MASK13) | jb;
        ka = (ja == query) ? IMAX : ka;
        kb = (jb == query) ? IMAX : kb;
        ins2(l, ka, kb);
    }
#pragma unroll
    for (int k = 0; k < KNN; ++k) mv[(wv * KNN + k) * QPB + lane] = l[k];
    __syncthreads();
    if (threadIdx.x < QPB) {
        int m[KNN];
#pragma unroll
        for (int k = 0; k < KNN; ++k) m[k] = IMAX;
#pragma unroll
        for (int e = 0; e < WPB; ++e) {
            int p[KNN];
#pragma unroll
            for (int k = 0; k < KNN; ++k) p[k] = mv[(e * KNN + k) * QPB + lane];
            merge_sorted(m, p);
        }
        const float* P2b = p2 + (size_t)batch * NPTS * 3;
        float s1x = 0, s1y = 0, s1z = 0, s2x = 0, s2y = 0, s2z = 0;
#pragma unroll
        for (int k = 0; k < KNN; ++k) {
            const int j = m[k] & (NPTS - 1);
            const float4 c = Wb[j];
            s1x += c.x; s1y += c.y; s1z += c.z;
            s2x += P2b[3 * j + 0]; s2y += P2b[3 * j + 1]; s2z += P2b[3 * j + 2];
        }
        const int q = qbase + threadIdx.x;
        const float p2x = P2b[3 * q + 0], p2y = P2b[3 * q + 1], p2z = P2b[3 * q + 2];
        const float dx = (s1x * 0.1f - qp.x) - (s2x * 0.1f - p2x);
        const float dy = (s1y * 0.1f - qp.y) - (s2y * 0.1f - p2y);
        const float dz = (s1z * 0.1f - qp.z) - (s2z * 0.1f - p2z);
        float v = fabsf(dx) + fabsf(dy) + fabsf(dz);
#pragma unroll
        for (int off = 32; off >= 1; off >>= 1) v += __shfl_down(v, off);
        if (threadIdx.x == 0)
            atomicAdd(out, v * (1.0f / (float)(NB * NPTS * 3)));
    }
}

// ---------------- launcher ----------------
extern "C" void kernel_launch(void* const* d_in, const int* in_sizes, int n_in,
                              void* d_out, int out_size, void* d_ws, size_t ws_size,
                              hipStream_t stream) {
    const float* p1 = (const float*)d_in[0];
    const float* p2 = (const float*)d_in[1];
    float* out = (float*)d_out;

    size_t off = 0;
    float4* w       = (float4*)d_ws;               off += (size_t)NB * NPTS * 16;
    int*    hist    = (int*)((char*)d_ws + off);   off += (size_t)NB * NC * 4;
    int*    starts  = (int*)((char*)d_ws + off);   off += (size_t)NB * (NC + 1) * 4 + 8;
    int*    cellof  = (int*)((char*)d_ws + off);   off += (size_t)NB * NPTS * 4;
    float4* wsorted = (float4*)((char*)d_ws + off); off += (size_t)NB * NPTS * 16;
    float4* p2s     = (float4*)((char*)d_ws + off); off += (size_t)NB * NPTS * 16;
    int*    nfail   = (int*)((char*)d_ws + off);   off += 16;
    int*    worklist= (int*)((char*)d_ws + off);   off += (size_t)NB * NPTS * 4;

    if (ws_size < off) {  // fallback: round-2 brute force
        hipMemsetAsync(out, 0, sizeof(float), stream);
        prep_pack<<<(NB * NPTS + 255) / 256, 256, 0, stream>>>(p1, w);
        knn_lap<<<NB * (NPTS / QPB), BLOCK, 0, stream>>>(w, p2, out);
        return;
    }

    hipMemsetAsync(hist, 0, (size_t)NB * NC * 4, stream);
    pack_bin<<<(NB * NPTS + 255) / 256, 256, 0, stream>>>(p1, w, hist, cellof);
    scan_cells<<<NB, 1024, 0, stream>>>(hist, starts, out, nfail);
    scatter_all<<<(NB * NPTS + 255) / 256, 256, 0, stream>>>(cellof, starts, hist,
                                                             w, p2, wsorted, p2s);
    phase1<<<NB * (NPTS / QPB), BLOCK, 0, stream>>>(wsorted, p2s, starts, out,
                                                    nfail, worklist);
    phase2<<<P2GRID, P2BLK, 0, stream>>>(wsorted, p2s, nfail, worklist, out);
}